// Round 4
// baseline (6015.923 us; speedup 1.0000x reference)
//
#include <hip/hip_runtime.h>

#define BATCH 8
#define N 32768
#define NPOINT 2048
#define NT 512               // threads per block (8 waves)
#define NW (NT / 64)

typedef __attribute__((ext_vector_type(2))) float f2;

// One block per batch.
//   x,y,temp : 96 named f2 vars pinned to arch VGPRs via asm "+v" constraints
//   z        : LDS (128 KiB, q = k*NT + t, conflict-free ds_read_b64)
// Per iteration: ONE barrier. Argmax tracked inline during the update, packed
// as u64 key (f32bits(max)<<32 | (32767-idx)) -> wave u64-max butterfly ->
// one LDS slot per wave (double-buffered) -> barrier -> redundant 8-way max.
// Bit-exact numpy semantics: contract off, (xx+yy)+zz order, lowest-index ties
// (strict > per lane ascending q; key low-field inverts idx for cross-lane).

#define REP32(M)  M(0)  M(1)  M(2)  M(3)  M(4)  M(5)  M(6)  M(7)  \
                  M(8)  M(9)  M(10) M(11) M(12) M(13) M(14) M(15) \
                  M(16) M(17) M(18) M(19) M(20) M(21) M(22) M(23) \
                  M(24) M(25) M(26) M(27) M(28) M(29) M(30) M(31)

__global__ __attribute__((amdgpu_flat_work_group_size(NT, NT),
                          amdgpu_waves_per_eu(2, 2)))
void fps_kernel(const float* __restrict__ pts_t,  // (B,3,N)
                float* __restrict__ out)          // (B,3,NPOINT)
{
#pragma clang fp contract(off)
    __shared__ f2 s_z[N / 2];                       // 128 KiB
    __shared__ unsigned long long s_red[2][NW];     // double-buffered

    const int b = blockIdx.x;
    const int t = threadIdx.x;
    const int wv = t >> 6;

    const float* __restrict__ px = pts_t + (size_t)b * 3 * N;
    const float* __restrict__ py = px + N;
    const float* __restrict__ pz = py + N;
    const f2* __restrict__ px2 = (const f2*)px;
    const f2* __restrict__ py2 = (const f2*)py;
    const f2* __restrict__ pz2 = (const f2*)pz;
    const float* s_zf = (const float*)s_z;
    float* outx = out + (size_t)b * 3 * NPOINT;
    float* outy = outx + NPOINT;
    float* outz = outy + NPOINT;

    // ---- declare 96 named f2 registers ----
#define DECL(k) f2 x##k, y##k, T##k;
    REP32(DECL)
#undef DECL

    // ---- load x,y into registers; z into LDS; init temps ----
#define LOADK(k) { const int q = (k) * NT + t;               \
                   x##k = px2[q];  y##k = py2[q];            \
                   s_z[q] = pz2[q];                          \
                   T##k = (f2){1e10f, 1e10f}; }
    REP32(LOADK)
#undef LOADK

    // ---- pin all 96 f2 values to arch VGPRs (VReg_64 class) ----
#define PIN4(a, b, c, d) asm("" : "+v"(a), "+v"(b), "+v"(c), "+v"(d));
#define PINGRP(k) PIN4(x##k, y##k, T##k, x##k)
    REP32(PINGRP)
#undef PINGRP
#undef PIN4

    // First selected index is 0 (reference: idx[0] = 0).
    float lx = px[0], ly = py[0], lz = pz[0];
    if (t == 0) { outx[0] = lx; outy[0] = ly; outz[0] = lz; }
    __syncthreads();

    for (int j = 1; j < NPOINT; ++j) {
        const f2 lx2 = (f2){lx, lx};
        const f2 ly2 = (f2){ly, ly};
        const f2 lz2 = (f2){lz, lz};

        // --- update temps vs pivot; inline (max, argmax) tracking ---
        float rm = -1.0f;
        int   ri = 0;
#define UPD(k) { const int q = (k) * NT + t;                           \
                 f2 dz = s_z[q] - lz2;                                 \
                 f2 dx = x##k - lx2;                                   \
                 f2 dy = y##k - ly2;                                   \
                 f2 s  = (dx * dx + dy * dy) + dz * dz; /* numpy order */ \
                 T##k.x = fminf(T##k.x, s.x);                          \
                 T##k.y = fminf(T##k.y, s.y);                          \
                 ri = (T##k.x > rm) ? 2 * q : ri;                      \
                 rm = fmaxf(rm, T##k.x);                               \
                 ri = (T##k.y > rm) ? 2 * q + 1 : ri;                  \
                 rm = fmaxf(rm, T##k.y); }
        REP32(UPD)
#undef UPD

        // --- pack (max, lowest-idx) into one u64 key; wave butterfly max ---
        unsigned long long key =
            ((unsigned long long)__float_as_uint(rm) << 32) |
            (unsigned int)(32767 - ri);
#pragma unroll
        for (int off = 32; off >= 1; off >>= 1) {
            unsigned long long o = __shfl_xor(key, off);
            key = (o > key) ? o : key;
        }
        if ((t & 63) == 0) s_red[j & 1][wv] = key;
        __syncthreads();                          // the ONLY barrier

        // --- redundant 8-way reduce (LDS broadcast reads) ---
        unsigned long long K = s_red[j & 1][0];
#pragma unroll
        for (int w = 1; w < NW; ++w) {
            unsigned long long o = s_red[j & 1][w];
            K = (o > K) ? o : K;
        }
        int sel = 32767 - (int)(unsigned int)(K & 0xFFFFFFFFu);
        sel = __builtin_amdgcn_readfirstlane(sel);

        lx = px[sel];                             // uniform scalar loads
        ly = py[sel];
        lz = s_zf[sel];                           // LDS broadcast read
        if (t == 0) { outx[j] = lx; outy[j] = ly; outz[j] = lz; }
    }
}

extern "C" void kernel_launch(void* const* d_in, const int* in_sizes, int n_in,
                              void* d_out, int out_size, void* d_ws, size_t ws_size,
                              hipStream_t stream) {
    // d_in[0]: points_xyz (B,N,3) — unused
    // d_in[1]: points_xyz_t (B,3,N)
    // d_in[2]: features_with_xyz (B,67,N) — unused
    const float* pts_t = (const float*)d_in[1];
    float* out = (float*)d_out;
    fps_kernel<<<BATCH, NT, 0, stream>>>(pts_t, out);
}